// Round 11
// baseline (654.199 us; speedup 1.0000x reference)
//
#include <hip/hip_runtime.h>
#include <cstddef>

#define NSLOPE 0.2f

constexpr int NN = 50000;
constexpr int EE = 800000;
constexpr int GG = 64;
constexpr int SCAN_B = 1024;

typedef unsigned short ushort_t;
typedef unsigned int uint_t;
typedef __bf16 bhalf;
typedef bhalf bhalf8 __attribute__((ext_vector_type(8)));
typedef float floatx4 __attribute__((ext_vector_type(4)));
typedef _Float16 half_t;
typedef half_t half2_t __attribute__((ext_vector_type(2)));

__device__ __forceinline__ ushort_t f2b(float f) {  // fp32 -> bf16 RNE
  unsigned int u = __float_as_uint(f);
  unsigned int r = (u + 0x7fffu + ((u >> 16) & 1u)) >> 16;
  return (ushort_t)r;
}
__device__ __forceinline__ float b2f(ushort_t b) {
  return __uint_as_float(((unsigned int)b) << 16);
}
__device__ __forceinline__ uint_t packh2(float a, float b) {
  half2_t h = {(half_t)a, (half_t)b};
  return __builtin_bit_cast(uint_t, h);
}
// z += dot2(ea_pair, w_pair) via V_DOT2_F32_F16 (fp32 accumulate)
__device__ __forceinline__ float dot2acc(uint_t ea, half2_t w, float c) {
  half2_t a = __builtin_bit_cast(half2_t, ea);
#if __has_builtin(__builtin_amdgcn_fdot2)
  return __builtin_amdgcn_fdot2(a, w, c, false);
#else
  return c + (float)a.x * (float)w.x + (float)a.y * (float)w.y;
#endif
}
// bare v_exp_f32: inputs are bounded logits (|x| < ~64), no range fixup needed
__device__ __forceinline__ float fexp2(float x) {
#if __has_builtin(__builtin_amdgcn_exp2f)
  return __builtin_amdgcn_exp2f(x);
#else
  return exp2f(x);
#endif
}

// 16-lane reduce-broadcast via DPP (quad_perm + row_ror): pure VALU, no LDS.
__device__ __forceinline__ float red16(float x) {
  int v = __builtin_bit_cast(int, x);
  x += __builtin_bit_cast(float, __builtin_amdgcn_update_dpp(0, v, 0xB1, 0xF, 0xF, true));   // xor1
  v = __builtin_bit_cast(int, x);
  x += __builtin_bit_cast(float, __builtin_amdgcn_update_dpp(0, v, 0x4E, 0xF, 0xF, true));   // xor2
  v = __builtin_bit_cast(int, x);
  x += __builtin_bit_cast(float, __builtin_amdgcn_update_dpp(0, v, 0x124, 0xF, 0xF, true));  // row_ror:4
  v = __builtin_bit_cast(int, x);
  x += __builtin_bit_cast(float, __builtin_amdgcn_update_dpp(0, v, 0x128, 0xF, 0xF, true));  // row_ror:8
  return x;
}

// ---------------- CSR build (dst-sorted edge permutation) ----------------
// int4-vectorized histogram: 4 edges/thread, coalesced 16B reads
__global__ void hist_kernel(const int* __restrict__ dst, int* __restrict__ hist, int E4) {
  int i = blockIdx.x * blockDim.x + threadIdx.x;
  if (i >= E4) return;
  int4 d = reinterpret_cast<const int4*>(dst)[i];
  atomicAdd(&hist[d.x], 1);
  atomicAdd(&hist[d.y], 1);
  atomicAdd(&hist[d.z], 1);
  atomicAdd(&hist[d.w], 1);
}

__global__ void scan_block_kernel(const int* __restrict__ in, int* __restrict__ out,
                                  int* __restrict__ bsum, int n) {
  __shared__ int tmp[SCAN_B];
  int gid = blockIdx.x * SCAN_B + threadIdx.x;
  int v = (gid < n) ? in[gid] : 0;
  tmp[threadIdx.x] = v;
  __syncthreads();
  for (int off = 1; off < SCAN_B; off <<= 1) {
    int t = (threadIdx.x >= off) ? tmp[threadIdx.x - off] : 0;
    __syncthreads();
    tmp[threadIdx.x] += t;
    __syncthreads();
  }
  if (gid < n) out[gid] = tmp[threadIdx.x];
  if (threadIdx.x == SCAN_B - 1) bsum[blockIdx.x] = tmp[threadIdx.x];
}

// finalize rowptr + init cursor; block offset computed in-kernel by per-wave
// shfl reduce of bsum[0..blockIdx.x-1] (nb<=64) — replaces scan_totals dispatch.
__global__ void add_offsets_kernel(int* __restrict__ rowptr, const int* __restrict__ bsum,
                                   int* __restrict__ cursor, int n, int nb) {
  int lane = threadIdx.x & 63;
  int bx = blockIdx.x;
  int v = (lane < nb && lane < bx) ? bsum[lane] : 0;
  v += __shfl_xor(v, 1);
  v += __shfl_xor(v, 2);
  v += __shfl_xor(v, 4);
  v += __shfl_xor(v, 8);
  v += __shfl_xor(v, 16);
  v += __shfl_xor(v, 32);
  int boff = v;  // exclusive prefix for this block, broadcast in wave
  int gid = bx * SCAN_B + threadIdx.x;
  if (gid == 0) { rowptr[0] = 0; cursor[0] = 0; }
  if (gid < n) {
    int t = rowptr[1 + gid] + boff;
    rowptr[1 + gid] = t;
    if (1 + gid < n) cursor[1 + gid] = t;
  }
}

// scatter pass A: place src + perm at the dst-sorted slot (4B random writes only;
// the old fused 36B random partial-line write paid RMW ownership per edge)
__global__ void scatter_pos_kernel(const int* __restrict__ dst, const int* __restrict__ src,
                                   int* __restrict__ cursor, int* __restrict__ srcp,
                                   int* __restrict__ perm, int E) {
  int e = blockIdx.x * blockDim.x + threadIdx.x;
  if (e >= E) return;
  int pos = atomicAdd(&cursor[dst[e]], 1);
  srcp[pos] = src[e];
  perm[pos] = e;
}

// scatter pass B: gather eattr rows (random 64B reads = exactly 1 line) and
// write packed f16 pairs COALESCED (streaming 32B writes, full lines).
__global__ void eah_build_kernel(const int* __restrict__ perm, const float* __restrict__ eattr,
                                 uint_t* __restrict__ eah, int E) {
  int pos = blockIdx.x * blockDim.x + threadIdx.x;
  if (pos >= E) return;
  int e = perm[pos];
  const float4* a = reinterpret_cast<const float4*>(eattr + (size_t)e * 16);
  float4 f0 = a[0], f1 = a[1], f2 = a[2], f3 = a[3];
  uint4 o0 = make_uint4(packh2(f0.x, f0.y), packh2(f0.z, f0.w),
                        packh2(f1.x, f1.y), packh2(f1.z, f1.w));
  uint4 o1 = make_uint4(packh2(f2.x, f2.y), packh2(f2.z, f2.w),
                        packh2(f3.x, f3.y), packh2(f3.z, f3.w));
  uint4* b = reinterpret_cast<uint4*>(eah + (size_t)pos * 8);
  b[0] = o0; b[1] = o1;
}

// per-dst mean edge_attr (self-loop fill_value='mean'), wave-per-row coalesced.
__global__ __launch_bounds__(256) void mean_attr_kernel(
    const int* __restrict__ rowptr, const uint_t* __restrict__ eah,
    uint_t* __restrict__ meanattr_h, int N) {
  const int lane = threadIdx.x & 63;
  int d = blockIdx.x * (blockDim.x >> 6) + (threadIdx.x >> 6);
  if (d >= N) return;
  int beg = rowptr[d], end = rowptr[d + 1];
  int k2 = lane & 7;
  int sub = lane >> 3;
  float ax = 0.f, ay = 0.f;
  for (int j = beg + sub; j < end; j += 8) {
    half2_t h = __builtin_bit_cast(half2_t, eah[(size_t)j * 8 + k2]);
    ax += (float)h.x; ay += (float)h.y;
  }
  ax += __shfl_xor(ax, 8);  ay += __shfl_xor(ay, 8);
  ax += __shfl_xor(ax, 16); ay += __shfl_xor(ay, 16);
  ax += __shfl_xor(ax, 32); ay += __shfl_xor(ay, 32);
  if (sub == 0) {
    int c = end - beg; if (c < 1) c = 1;
    float inv = 1.f / (float)c;
    meanattr_h[(size_t)d * 8 + k2] = packh2(ax * inv, ay * inv);
  }
}

// merged prep: y=0..5 weight transposes Wt[n][k]=bf16(W[k][n]); y=6..8 We pack + att scale
__global__ void prep_all_kernel(const float* W0, ushort_t* T0, int n0,
                                const float* W1, ushort_t* T1, int n1,
                                const float* W2, ushort_t* T2, int n2,
                                const float* W3, ushort_t* T3, int n3,
                                const float* W4, ushort_t* T4, int n4,
                                const float* W5, ushort_t* T5, int n5,
                                const float* We0, const float* att0, uint_t* w0, float* a0,
                                const float* We1, const float* att1, uint_t* w1, float* a1,
                                const float* We2, const float* att2, uint_t* w2, float* a2) {
  int idx = blockIdx.x * blockDim.x + threadIdx.x;
  int y = blockIdx.y;
  if (y < 6) {
    const float* W; ushort_t* T; int Nc;
    switch (y) {
      case 0: W = W0; T = T0; Nc = n0; break;
      case 1: W = W1; T = T1; Nc = n1; break;
      case 2: W = W2; T = T2; Nc = n2; break;
      case 3: W = W3; T = T3; Nc = n3; break;
      case 4: W = W4; T = T4; Nc = n4; break;
      default: W = W5; T = T5; Nc = n5; break;
    }
    if (idx >= Nc * 128) return;
    int n = idx >> 7, k = idx & 127;
    T[idx] = f2b(W[(size_t)k * Nc + n]);
  } else {
    const float* We; const float* att; uint_t* wp; float* ap; int C;
    switch (y) {
      case 6: We = We0; att = att0; wp = w0; ap = a0; C = 128; break;
      case 7: We = We1; att = att1; wp = w1; ap = a1; C = 128; break;
      default: We = We2; att = att2; wp = w2; ap = a2; C = 256; break;
    }
    if (idx >= 9 * C) return;
    if (idx < 8 * C) {
      int sh = (C == 256) ? 8 : 7;
      int k2 = idx >> sh, ch = idx & (C - 1);
      wp[idx] = packh2(We[(size_t)(2 * k2) * C + ch], We[(size_t)(2 * k2 + 1) * C + ch]);
    } else {
      int ch = idx - 8 * C;
      ap[ch] = att[ch] * 1.44269504f;  // log2(e)
    }
  }
}

// -------- dual bf16 MFMA GEMM (B^T layout): Y{0,1} = bf16(A @ W{0,1} + b{0,1}) --------
// A-tile staged ONCE per block; the two halves loop inside (re-stage B only).
template <typename TA>
__global__ __launch_bounds__(256) void gemm_bt_dual_bf16(
    const TA* __restrict__ Xb,
    const ushort_t* __restrict__ Wt0, const float* __restrict__ b0, ushort_t* __restrict__ Y0,
    const ushort_t* __restrict__ Wt1, const float* __restrict__ b1, ushort_t* __restrict__ Y1,
    int M, int Nc) {
  constexpr int K = 128, BM = 128, LDT = 136;
  __shared__ ushort_t Als[BM * LDT];
  __shared__ ushort_t Bls[BM * LDT];
  int r0 = blockIdx.x * BM;
  int col0 = blockIdx.y * 128;  // column block (gridDim.y = Nc/128)
  int tid = threadIdx.x;
  int rl = tid >> 5;
  int kq = (tid & 31) * 4;
  // stage A once
#pragma unroll
  for (int s = 0; s < 16; ++s) {
    int row = rl + s * 8;
    int grow = r0 + row;
    ushort4 v = make_ushort4(0, 0, 0, 0);
    if (grow < M) {
      if constexpr (sizeof(TA) == 4) {
        float4 f = *reinterpret_cast<const float4*>(Xb + (size_t)grow * K + kq);
        v = make_ushort4(f2b(f.x), f2b(f.y), f2b(f.z), f2b(f.w));
      } else {
        v = *reinterpret_cast<const ushort4*>(Xb + (size_t)grow * K + kq);
      }
    }
    *reinterpret_cast<ushort4*>(&Als[row * LDT + kq]) = v;
  }
  int lane = tid & 63;
  int w = tid >> 6;
  int m0 = (w >> 1) * 64;
  int n0 = (w & 1) * 64;
  int rin = lane & 15, quad = lane >> 4;

  for (int half = 0; half < 2; ++half) {
    const ushort_t* Wt = half ? Wt1 : Wt0;
    const float* bias = half ? b1 : b0;
    ushort_t* Y = half ? Y1 : Y0;
    __syncthreads();  // half0: A-stage visible; half1: prev Bls reads done
#pragma unroll
    for (int s = 0; s < 16; ++s) {
      int row = rl + s * 8;
      ushort4 wv = *reinterpret_cast<const ushort4*>(Wt + (size_t)(col0 + row) * K + kq);
      *reinterpret_cast<ushort4*>(&Bls[row * LDT + kq]) = wv;
    }
    __syncthreads();  // A and B staged
    floatx4 acc[4][4];
#pragma unroll
    for (int i = 0; i < 4; ++i)
#pragma unroll
      for (int j = 0; j < 4; ++j) acc[i][j] = (floatx4){0.f, 0.f, 0.f, 0.f};
#pragma unroll
    for (int kt = 0; kt < 4; ++kt) {
      int ko = kt * 32 + quad * 8;
      bhalf8 af[4], bf[4];
#pragma unroll
      for (int i = 0; i < 4; ++i)
        af[i] = *reinterpret_cast<const bhalf8*>(&Als[(m0 + i * 16 + rin) * LDT + ko]);
#pragma unroll
      for (int i = 0; i < 4; ++i)
        bf[i] = *reinterpret_cast<const bhalf8*>(&Bls[(n0 + i * 16 + rin) * LDT + ko]);
#pragma unroll
      for (int mi = 0; mi < 4; ++mi)
#pragma unroll
        for (int ni = 0; ni < 4; ++ni)
          acc[mi][ni] = __builtin_amdgcn_mfma_f32_16x16x32_bf16(af[mi], bf[ni], acc[mi][ni], 0, 0, 0);
    }
#pragma unroll
    for (int ni = 0; ni < 4; ++ni) {
      int gcol = col0 + n0 + ni * 16 + rin;
      float bb = bias[gcol];
#pragma unroll
      for (int mi = 0; mi < 4; ++mi) {
        int growb = r0 + m0 + mi * 16 + quad * 4;
#pragma unroll
        for (int r = 0; r < 4; ++r) {
          int grow = growb + r;
          if (grow < M) Y[(size_t)grow * Nc + gcol] = f2b(acc[mi][ni][r] + bb);
        }
      }
    }
  }
}

// ---------------- bf16 vector load/store helpers ----------------
template <int VPL>
__device__ __forceinline__ void loadb(const ushort_t* p, float* v) {
  if constexpr (VPL == 2) {
    ushort2 t = *reinterpret_cast<const ushort2*>(p);
    v[0] = b2f(t.x); v[1] = b2f(t.y);
  } else {
    ushort4 t = *reinterpret_cast<const ushort4*>(p);
    v[0] = b2f(t.x); v[1] = b2f(t.y); v[2] = b2f(t.z); v[3] = b2f(t.w);
  }
}
template <int VPL>
__device__ __forceinline__ void storeb(ushort_t* p, const float* v) {
  if constexpr (VPL == 2) {
    *reinterpret_cast<ushort2*>(p) = make_ushort2(f2b(v[0]), f2b(v[1]));
  } else {
    *reinterpret_cast<ushort4*>(p) = make_ushort4(f2b(v[0]), f2b(v[1]), f2b(v[2]), f2b(v[3]));
  }
}

// per-edge logit: leaky-relu(xl+xr+ea@We) . att (ea@We via 8 dot2 f16 MACs/channel)
template <int VPL>
__device__ __forceinline__ float lrelu_dot(const float* xv, const float* rv,
                                           const half2_t (*wepk)[VPL], const float* areg,
                                           const uint_t* ea) {
  float part = 0.f;
#pragma unroll
  for (int j = 0; j < VPL; ++j) {
    float z = xv[j] + rv[j];
#pragma unroll
    for (int k2 = 0; k2 < 8; ++k2) z = dot2acc(ea[k2], wepk[k2][j], z);
    float zl = fmaxf(z, NSLOPE * z);  // leaky-relu (slope<1)
    part = fmaf(zl, areg[j], part);
  }
  return red16(part);  // per-head (16-lane) reduce-broadcast, DPP only
}

// batched softmax update over EB edges
template <int EB, int VPL, int C>
__device__ __forceinline__ void process_group(
    const int* __restrict__ srcp, const uint_t* __restrict__ eah, int j,
    const ushort_t* __restrict__ xl, int lane, const float* rv,
    const half2_t (*wepk)[VPL], const float* areg,
    float& s, float* acc) {
  int sn[EB];
#pragma unroll
  for (int u = 0; u < EB; ++u) sn[u] = srcp[j + u];
  float xv[EB][VPL];
#pragma unroll
  for (int u = 0; u < EB; ++u) loadb<VPL>(xl + (size_t)sn[u] * C + lane * VPL, xv[u]);
  float lg[EB];
#pragma unroll
  for (int u = 0; u < EB; ++u) {
    const uint4* ap4 = reinterpret_cast<const uint4*>(eah + (size_t)(j + u) * 8);
    uint4 e0 = ap4[0], e1 = ap4[1];
    uint_t ea[8] = {e0.x, e0.y, e0.z, e0.w, e1.x, e1.y, e1.z, e1.w};
    lg[u] = lrelu_dot<VPL>(xv[u], rv, wepk, areg, ea);
  }
  float p[EB], ps = 0.f;
#pragma unroll
  for (int u = 0; u < EB; ++u) { p[u] = fexp2(lg[u]); ps += p[u]; }
  s += ps;
#pragma unroll
  for (int jj = 0; jj < VPL; ++jj) {
    float t = p[0] * xv[0][jj];
#pragma unroll
    for (int u = 1; u < EB; ++u) t = fmaf(p[u], xv[u][jj], t);
    acc[jj] += t;
  }
}

// single edge with explicit src + packed ea pairs (self-loop path)
template <int VPL, int C>
__device__ __forceinline__ void process_edge(
    int sn, const uint_t* ea,
    const ushort_t* __restrict__ xl, int lane, const float* rv,
    const half2_t (*wepk)[VPL], const float* areg,
    float& s, float* acc) {
  float xv[VPL];
  loadb<VPL>(xl + (size_t)sn * C + lane * VPL, xv);
  float lg = lrelu_dot<VPL>(xv, rv, wepk, areg, ea);
  float p = fexp2(lg);
  s += p;
#pragma unroll
  for (int jj = 0; jj < VPL; ++jj) acc[jj] = fmaf(p, xv[jj], acc[jj]);
}

// ---------------- fused GATv2 edge+softmax+aggregate: ONE 64-thread block per dst ----
// R4 exact form (best measured: 118.6us). Throughput-capped on beyond-L2 path
// (~3.2 B/cy/CU); all parallelism levers (pipelining, 2-wave, persistent, nt)
// measured null-or-negative. This is the floor for this access pattern.
template <int C, bool FINAL>
__global__ __launch_bounds__(64) void gat_fused_kernel(
    const int* __restrict__ rowptr,
    const int* __restrict__ srcp, const uint_t* __restrict__ eah,
    const uint_t* __restrict__ meanattr_h,
    const ushort_t* __restrict__ xl, const ushort_t* __restrict__ xr,
    const uint_t* __restrict__ wep,   // [8*C] packed f16 k-pairs of We
    const float* __restrict__ atts,   // [C] att * log2(e)
    const float* __restrict__ bias, ushort_t* __restrict__ hout, int N) {
  constexpr int VPL = C / 64;
  const int lane = threadIdx.x & 63;
  int d = blockIdx.x;
  if (d >= N) return;

  half2_t wepk[8][VPL];
  float areg[VPL];
#pragma unroll
  for (int k2 = 0; k2 < 8; ++k2)
#pragma unroll
    for (int jj = 0; jj < VPL; ++jj)
      wepk[k2][jj] = __builtin_bit_cast(half2_t, wep[k2 * C + lane * VPL + jj]);
#pragma unroll
  for (int jj = 0; jj < VPL; ++jj) areg[jj] = atts[lane * VPL + jj];

  int beg = rowptr[d], end = rowptr[d + 1];
  float rv[VPL];
  loadb<VPL>(xr + (size_t)d * C + lane * VPL, rv);

  float s = 0.f;
  float acc[VPL];
#pragma unroll
  for (int jj = 0; jj < VPL; ++jj) acc[jj] = 0.f;

  int j = beg;
  if constexpr (C == 128) {
    for (; j + 8 <= end; j += 8)
      process_group<8, VPL, C>(srcp, eah, j, xl, lane, rv, wepk, areg, s, acc);
  }
  for (; j + 4 <= end; j += 4)
    process_group<4, VPL, C>(srcp, eah, j, xl, lane, rv, wepk, areg, s, acc);
  for (; j + 2 <= end; j += 2)
    process_group<2, VPL, C>(srcp, eah, j, xl, lane, rv, wepk, areg, s, acc);
  for (; j < end; ++j)
    process_group<1, VPL, C>(srcp, eah, j, xl, lane, rv, wepk, areg, s, acc);

  // self loop with mean edge_attr (fill_value='mean')
  {
    const uint4* mp4 = reinterpret_cast<const uint4*>(meanattr_h + (size_t)d * 8);
    uint4 e0 = mp4[0], e1 = mp4[1];
    uint_t ea[8] = {e0.x, e0.y, e0.z, e0.w, e1.x, e1.y, e1.z, e1.w};
    process_edge<VPL, C>(d, ea, xl, lane, rv, wepk, areg, s, acc);
  }

  float inv = 1.f / (s + 1e-16f);
  if constexpr (!FINAL) {
    float res[VPL];
#pragma unroll
    for (int jj = 0; jj < VPL; ++jj) {
      float v = acc[jj] * inv + bias[lane * VPL + jj];
      res[jj] = v > 0.f ? v : 0.f;
    }
    storeb<VPL>(hout + (size_t)d * C + lane * VPL, res);
  } else {
    float v[VPL];
#pragma unroll
    for (int jj = 0; jj < VPL; ++jj) v[jj] = acc[jj] * inv;
#pragma unroll
    for (int jj = 0; jj < VPL; ++jj) {
      v[jj] += __shfl_xor(v[jj], 16);
      v[jj] += __shfl_xor(v[jj], 32);
    }
    if (lane < 16) {
      float res[VPL];
#pragma unroll
      for (int jj = 0; jj < VPL; ++jj) {
        float val = 0.25f * v[jj] + bias[lane * VPL + jj];
        res[jj] = val > 0.f ? val : 0.f;
      }
      storeb<VPL>(hout + (size_t)d * 64 + lane * VPL, res);
    }
  }
}

// ---------------- global mean pool: segmented reduction (batch is SORTED) ----------------
__global__ __launch_bounds__(256) void pool_kernel(
    const ushort_t* __restrict__ h3, const int* __restrict__ batch,
    float* __restrict__ gsum, float* __restrict__ gcnt, int N) {
  const int lane = threadIdx.x & 63;
  const int w = blockIdx.x * (blockDim.x >> 6) + (threadIdx.x >> 6);
  const int nw = gridDim.x * (blockDim.x >> 6);
  const int chunk = (N + nw - 1) / nw;
  int i0 = w * chunk;
  int i1 = i0 + chunk; if (i1 > N) i1 = N;
  if (i0 >= i1) return;
  int cur = batch[i0];
  float acc = 0.f;
  int cnt = 0;
  for (int i = i0; i < i1; ++i) {
    int g = batch[i];
    if (g != cur) {
      atomicAdd(&gsum[(size_t)cur * 64 + lane], acc);
      if (lane == 0) atomicAdd(&gcnt[cur], (float)cnt);
      acc = 0.f; cnt = 0; cur = g;
    }
    acc += b2f(h3[(size_t)i * 64 + lane]);
    ++cnt;
  }
  atomicAdd(&gsum[(size_t)cur * 64 + lane], acc);
  if (lane == 0) atomicAdd(&gcnt[cur], (float)cnt);
}

__global__ void final_kernel(const float* __restrict__ gsum, const float* __restrict__ gcnt,
                             const float* __restrict__ Wlin, const float* __restrict__ blin,
                             float* __restrict__ out) {
  int idx = blockIdx.x * blockDim.x + threadIdx.x;
  if (idx >= GG * 16) return;
  int g = idx >> 4, o = idx & 15;
  float c = gcnt[g];
  c = c > 1.f ? c : 1.f;
  float inv = 1.f / c;
  float acc = blin[o];
  for (int f = 0; f < 64; ++f) acc = fmaf(gsum[(size_t)g * 64 + f] * inv, Wlin[f * 16 + o], acc);
  out[idx] = acc;
}

// ---------------- launch ----------------
extern "C" void kernel_launch(void* const* d_in, const int* in_sizes, int n_in,
                              void* d_out, int out_size, void* d_ws, size_t ws_size,
                              hipStream_t stream) {
  (void)in_sizes; (void)n_in; (void)out_size; (void)ws_size;
  const float* x     = (const float*)d_in[0];
  const int*   eidx  = (const int*)d_in[1];
  const int*   batch = (const int*)d_in[2];
  const float* eattr = (const float*)d_in[3];
  const float* Wl0 = (const float*)d_in[4];  const float* bl0 = (const float*)d_in[5];
  const float* Wr0 = (const float*)d_in[6];  const float* br0 = (const float*)d_in[7];
  const float* We0 = (const float*)d_in[8];  const float* att0 = (const float*)d_in[9];
  const float* bo0 = (const float*)d_in[10];
  const float* Wlh = (const float*)d_in[11]; const float* blh = (const float*)d_in[12];
  const float* Wrh = (const float*)d_in[13]; const float* brh = (const float*)d_in[14];
  const float* Weh = (const float*)d_in[15]; const float* atth = (const float*)d_in[16];
  const float* boh = (const float*)d_in[17];
  const float* Wlf = (const float*)d_in[18]; const float* blf = (const float*)d_in[19];
  const float* Wrf = (const float*)d_in[20]; const float* brf = (const float*)d_in[21];
  const float* Wef = (const float*)d_in[22]; const float* attf = (const float*)d_in[23];
  const float* bof = (const float*)d_in[24];
  const float* Wlin = (const float*)d_in[25]; const float* blin = (const float*)d_in[26];

  const int* src = eidx;
  const int* dst = eidx + EE;

  char* ws = (char*)d_ws;
  size_t off = 0;
  auto take = [&](size_t bytes) -> void* {
    void* p = ws + off;
    off += (bytes + 1023) & ~(size_t)1023;
    return p;
  };
  ushort_t* xl     = (ushort_t*)take((size_t)NN * 256 * 2);
  ushort_t* xr     = (ushort_t*)take((size_t)NN * 256 * 2);
  ushort_t* hb     = (ushort_t*)take((size_t)NN * 128 * 2);   // layer io (bf16)
  uint_t* meanattr_h = (uint_t*)take((size_t)NN * 8 * 4);     // f16 pairs
  // hist, gsum, gcnt adjacent: ONE memset covers all three
  int* hist        = (int*)take((size_t)NN * 4);              // pads to 200704
  float* gsum      = (float*)take((size_t)GG * 64 * 4);       // 16384
  float* gcnt     = (float*)take((size_t)GG * 4);             // 256
  int* rowptr      = (int*)take((size_t)(NN + 1) * 4);
  int* cursor      = (int*)take((size_t)NN * 4);
  int* bsum        = (int*)take(256);
  ushort_t* wtl0   = (ushort_t*)take((size_t)128 * 128 * 2);
  ushort_t* wtr0   = (ushort_t*)take((size_t)128 * 128 * 2);
  ushort_t* wtlh   = (ushort_t*)take((size_t)128 * 128 * 2);
  ushort_t* wtrh   = (ushort_t*)take((size_t)128 * 128 * 2);
  ushort_t* wtlf   = (ushort_t*)take((size_t)256 * 128 * 2);
  ushort_t* wtrf   = (ushort_t*)take((size_t)256 * 128 * 2);
  int* srcp        = (int*)take((size_t)EE * 4);
  int* perm        = (int*)take((size_t)EE * 4);
  uint_t* eah      = (uint_t*)take((size_t)EE * 8 * 4);
  uint_t* we0p     = (uint_t*)take((size_t)8 * 128 * 4);
  uint_t* wehp     = (uint_t*)take((size_t)8 * 128 * 4);
  uint_t* wefp     = (uint_t*)take((size_t)8 * 256 * 4);
  float* att0s     = (float*)take((size_t)128 * 4);
  float* atths     = (float*)take((size_t)128 * 4);
  float* attfs     = (float*)take((size_t)256 * 4);

  // ---- CSR by dst (dst fixed across layers; rebuilt every call) ----
  // hist (padded 200704) + gsum (16384) + gcnt (256) are contiguous in ws
  hipMemsetAsync(hist, 0, 200704 + 16384 + 256, stream);
  hist_kernel<<<(EE / 4 + 255) / 256, 256, 0, stream>>>(dst, hist, EE / 4);
  int nsb = (NN + SCAN_B - 1) / SCAN_B;   // 49 (<= 64 for in-kernel wave reduce)
  scan_block_kernel<<<nsb, SCAN_B, 0, stream>>>(hist, rowptr + 1, bsum, NN);
  add_offsets_kernel<<<nsb, SCAN_B, 0, stream>>>(rowptr, bsum, cursor, NN, nsb);
  scatter_pos_kernel<<<(EE + 255) / 256, 256, 0, stream>>>(dst, src, cursor, srcp, perm, EE);
  eah_build_kernel<<<(EE + 255) / 256, 256, 0, stream>>>(perm, eattr, eah, EE);
  mean_attr_kernel<<<(NN + 3) / 4, 256, 0, stream>>>(rowptr, eah, meanattr_h, NN);
  prep_all_kernel<<<dim3(128, 9), 256, 0, stream>>>(
      Wl0, wtl0, 128, Wr0, wtr0, 128, Wlh, wtlh, 128, Wrh, wtrh, 128,
      Wlf, wtlf, 256, Wrf, wtrf, 256,
      We0, att0, we0p, att0s, Weh, atth, wehp, atths, Wef, attf, wefp, attfs);

  const int GEMM_MB = (NN + 127) / 128;

  // ---- Layer 1 (C=128): GEMM reads fp32 x directly (f2b fused into stage) ----
  gemm_bt_dual_bf16<float><<<dim3(GEMM_MB, 1), 256, 0, stream>>>(
      x, wtl0, bl0, xl, wtr0, br0, xr, NN, 128);
  gat_fused_kernel<128, false><<<NN, 64, 0, stream>>>(
      rowptr, srcp, eah, meanattr_h, xl, xr, we0p, att0s, bo0, hb, NN);
  // ---- Layer 2 (C=128) ----
  gemm_bt_dual_bf16<ushort_t><<<dim3(GEMM_MB, 1), 256, 0, stream>>>(
      hb, wtlh, blh, xl, wtrh, brh, xr, NN, 128);
  gat_fused_kernel<128, false><<<NN, 64, 0, stream>>>(
      rowptr, srcp, eah, meanattr_h, xl, xr, wehp, atths, boh, hb, NN);
  // ---- Layer 3 (C=256, mean over heads) ----
  gemm_bt_dual_bf16<ushort_t><<<dim3(GEMM_MB, 2), 256, 0, stream>>>(
      hb, wtlf, blf, xl, wtrf, brf, xr, NN, 256);
  gat_fused_kernel<256, true><<<NN, 64, 0, stream>>>(
      rowptr, srcp, eah, meanattr_h, xl, xr, wefp, attfs, bof, hb, NN);
  // ---- pool + final linear ----
  pool_kernel<<<128, 256, 0, stream>>>(hb, batch, gsum, gcnt, NN);
  final_kernel<<<4, 256, 0, stream>>>(gsum, gcnt, Wlin, blin, (float*)d_out);
}

// Round 12
// 634.114 us; speedup vs baseline: 1.0317x; 1.0317x over previous
//
#include <hip/hip_runtime.h>
#include <cstddef>

#define NSLOPE 0.2f

constexpr int NN = 50000;
constexpr int EE = 800000;
constexpr int GG = 64;
constexpr int SCAN_B = 1024;

typedef unsigned short ushort_t;
typedef unsigned int uint_t;
typedef __bf16 bhalf;
typedef bhalf bhalf8 __attribute__((ext_vector_type(8)));
typedef float floatx4 __attribute__((ext_vector_type(4)));
typedef _Float16 half_t;
typedef half_t half2_t __attribute__((ext_vector_type(2)));

__device__ __forceinline__ ushort_t f2b(float f) {  // fp32 -> bf16 RNE
  unsigned int u = __float_as_uint(f);
  unsigned int r = (u + 0x7fffu + ((u >> 16) & 1u)) >> 16;
  return (ushort_t)r;
}
__device__ __forceinline__ float b2f(ushort_t b) {
  return __uint_as_float(((unsigned int)b) << 16);
}
__device__ __forceinline__ uint_t packh2(float a, float b) {
  half2_t h = {(half_t)a, (half_t)b};
  return __builtin_bit_cast(uint_t, h);
}
// z += dot2(ea_pair, w_pair) via V_DOT2_F32_F16 (fp32 accumulate)
__device__ __forceinline__ float dot2acc(uint_t ea, half2_t w, float c) {
  half2_t a = __builtin_bit_cast(half2_t, ea);
#if __has_builtin(__builtin_amdgcn_fdot2)
  return __builtin_amdgcn_fdot2(a, w, c, false);
#else
  return c + (float)a.x * (float)w.x + (float)a.y * (float)w.y;
#endif
}
// bare v_exp_f32: inputs are bounded logits (|x| < ~64), no range fixup needed
__device__ __forceinline__ float fexp2(float x) {
#if __has_builtin(__builtin_amdgcn_exp2f)
  return __builtin_amdgcn_exp2f(x);
#else
  return exp2f(x);
#endif
}

// 16-lane reduce-broadcast via DPP (quad_perm + row_ror): pure VALU, no LDS.
__device__ __forceinline__ float red16(float x) {
  int v = __builtin_bit_cast(int, x);
  x += __builtin_bit_cast(float, __builtin_amdgcn_update_dpp(0, v, 0xB1, 0xF, 0xF, true));   // xor1
  v = __builtin_bit_cast(int, x);
  x += __builtin_bit_cast(float, __builtin_amdgcn_update_dpp(0, v, 0x4E, 0xF, 0xF, true));   // xor2
  v = __builtin_bit_cast(int, x);
  x += __builtin_bit_cast(float, __builtin_amdgcn_update_dpp(0, v, 0x124, 0xF, 0xF, true));  // row_ror:4
  v = __builtin_bit_cast(int, x);
  x += __builtin_bit_cast(float, __builtin_amdgcn_update_dpp(0, v, 0x128, 0xF, 0xF, true));  // row_ror:8
  return x;
}

// ---------------- CSR build (dst-sorted edge permutation) ----------------
// int4-vectorized histogram: 4 edges/thread, coalesced 16B reads
__global__ void hist_kernel(const int* __restrict__ dst, int* __restrict__ hist, int E4) {
  int i = blockIdx.x * blockDim.x + threadIdx.x;
  if (i >= E4) return;
  int4 d = reinterpret_cast<const int4*>(dst)[i];
  atomicAdd(&hist[d.x], 1);
  atomicAdd(&hist[d.y], 1);
  atomicAdd(&hist[d.z], 1);
  atomicAdd(&hist[d.w], 1);
}

__global__ void scan_block_kernel(const int* __restrict__ in, int* __restrict__ out,
                                  int* __restrict__ bsum, int n) {
  __shared__ int tmp[SCAN_B];
  int gid = blockIdx.x * SCAN_B + threadIdx.x;
  int v = (gid < n) ? in[gid] : 0;
  tmp[threadIdx.x] = v;
  __syncthreads();
  for (int off = 1; off < SCAN_B; off <<= 1) {
    int t = (threadIdx.x >= off) ? tmp[threadIdx.x - off] : 0;
    __syncthreads();
    tmp[threadIdx.x] += t;
    __syncthreads();
  }
  if (gid < n) out[gid] = tmp[threadIdx.x];
  if (threadIdx.x == SCAN_B - 1) bsum[blockIdx.x] = tmp[threadIdx.x];
}

// finalize rowptr + init cursor; block offset computed in-kernel by per-wave
// shfl reduce of bsum[0..blockIdx.x-1] (nb<=64) — no separate scan_totals dispatch.
__global__ void add_offsets_kernel(int* __restrict__ rowptr, const int* __restrict__ bsum,
                                   int* __restrict__ cursor, int n, int nb) {
  int lane = threadIdx.x & 63;
  int bx = blockIdx.x;
  int v = (lane < nb && lane < bx) ? bsum[lane] : 0;
  v += __shfl_xor(v, 1);
  v += __shfl_xor(v, 2);
  v += __shfl_xor(v, 4);
  v += __shfl_xor(v, 8);
  v += __shfl_xor(v, 16);
  v += __shfl_xor(v, 32);
  int boff = v;  // exclusive prefix for this block, broadcast in wave
  int gid = bx * SCAN_B + threadIdx.x;
  if (gid == 0) { rowptr[0] = 0; cursor[0] = 0; }
  if (gid < n) {
    int t = rowptr[1 + gid] + boff;
    rowptr[1 + gid] = t;
    if (1 + gid < n) cursor[1 + gid] = t;
  }
}

// fused scatter: place edge directly at its dst-sorted slot, pack edge attrs f16.
// (R11's split into 4B-write + gather-pass measured -11us; fused form restored.)
__global__ void scatter_fused_kernel(const int* __restrict__ dst, const int* __restrict__ src,
                                     const float* __restrict__ eattr, int* __restrict__ cursor,
                                     int* __restrict__ srcp, uint_t* __restrict__ eah, int E) {
  int e = blockIdx.x * blockDim.x + threadIdx.x;
  if (e >= E) return;
  const float4* a = reinterpret_cast<const float4*>(eattr + (size_t)e * 16);
  float4 f0 = a[0], f1 = a[1], f2 = a[2], f3 = a[3];
  int pos = atomicAdd(&cursor[dst[e]], 1);
  srcp[pos] = src[e];
  uint4 o0 = make_uint4(packh2(f0.x, f0.y), packh2(f0.z, f0.w),
                        packh2(f1.x, f1.y), packh2(f1.z, f1.w));
  uint4 o1 = make_uint4(packh2(f2.x, f2.y), packh2(f2.z, f2.w),
                        packh2(f3.x, f3.y), packh2(f3.z, f3.w));
  uint4* b = reinterpret_cast<uint4*>(eah + (size_t)pos * 8);
  b[0] = o0; b[1] = o1;
}

// per-dst mean edge_attr (self-loop fill_value='mean'), wave-per-row coalesced.
__global__ __launch_bounds__(256) void mean_attr_kernel(
    const int* __restrict__ rowptr, const uint_t* __restrict__ eah,
    uint_t* __restrict__ meanattr_h, int N) {
  const int lane = threadIdx.x & 63;
  int d = blockIdx.x * (blockDim.x >> 6) + (threadIdx.x >> 6);
  if (d >= N) return;
  int beg = rowptr[d], end = rowptr[d + 1];
  int k2 = lane & 7;
  int sub = lane >> 3;
  float ax = 0.f, ay = 0.f;
  for (int j = beg + sub; j < end; j += 8) {
    half2_t h = __builtin_bit_cast(half2_t, eah[(size_t)j * 8 + k2]);
    ax += (float)h.x; ay += (float)h.y;
  }
  ax += __shfl_xor(ax, 8);  ay += __shfl_xor(ay, 8);
  ax += __shfl_xor(ax, 16); ay += __shfl_xor(ay, 16);
  ax += __shfl_xor(ax, 32); ay += __shfl_xor(ay, 32);
  if (sub == 0) {
    int c = end - beg; if (c < 1) c = 1;
    float inv = 1.f / (float)c;
    meanattr_h[(size_t)d * 8 + k2] = packh2(ax * inv, ay * inv);
  }
}

// merged prep: y=0..5 weight transposes Wt[n][k]=bf16(W[k][n]); y=6..8 We pack + att scale
__global__ void prep_all_kernel(const float* W0, ushort_t* T0, int n0,
                                const float* W1, ushort_t* T1, int n1,
                                const float* W2, ushort_t* T2, int n2,
                                const float* W3, ushort_t* T3, int n3,
                                const float* W4, ushort_t* T4, int n4,
                                const float* W5, ushort_t* T5, int n5,
                                const float* We0, const float* att0, uint_t* w0, float* a0,
                                const float* We1, const float* att1, uint_t* w1, float* a1,
                                const float* We2, const float* att2, uint_t* w2, float* a2) {
  int idx = blockIdx.x * blockDim.x + threadIdx.x;
  int y = blockIdx.y;
  if (y < 6) {
    const float* W; ushort_t* T; int Nc;
    switch (y) {
      case 0: W = W0; T = T0; Nc = n0; break;
      case 1: W = W1; T = T1; Nc = n1; break;
      case 2: W = W2; T = T2; Nc = n2; break;
      case 3: W = W3; T = T3; Nc = n3; break;
      case 4: W = W4; T = T4; Nc = n4; break;
      default: W = W5; T = T5; Nc = n5; break;
    }
    if (idx >= Nc * 128) return;
    int n = idx >> 7, k = idx & 127;
    T[idx] = f2b(W[(size_t)k * Nc + n]);
  } else {
    const float* We; const float* att; uint_t* wp; float* ap; int C;
    switch (y) {
      case 6: We = We0; att = att0; wp = w0; ap = a0; C = 128; break;
      case 7: We = We1; att = att1; wp = w1; ap = a1; C = 128; break;
      default: We = We2; att = att2; wp = w2; ap = a2; C = 256; break;
    }
    if (idx >= 9 * C) return;
    if (idx < 8 * C) {
      int sh = (C == 256) ? 8 : 7;
      int k2 = idx >> sh, ch = idx & (C - 1);
      wp[idx] = packh2(We[(size_t)(2 * k2) * C + ch], We[(size_t)(2 * k2 + 1) * C + ch]);
    } else {
      int ch = idx - 8 * C;
      ap[ch] = att[ch] * 1.44269504f;  // log2(e)
    }
  }
}

// -------- dual bf16 MFMA GEMM (B^T layout): Y{0,1} = bf16(A @ W{0,1} + b{0,1}) --------
// BM=64: 782 blocks (~3/CU) instead of 391 (~1.5/CU). These GEMMs are small and
// latency-exposed, not MFMA-bound — the prior grid starved the latency hiding.
// A-tile staged ONCE per block; the two halves loop inside (re-stage B only).
template <typename TA>
__global__ __launch_bounds__(256) void gemm_bt_dual_bf16(
    const TA* __restrict__ Xb,
    const ushort_t* __restrict__ Wt0, const float* __restrict__ b0, ushort_t* __restrict__ Y0,
    const ushort_t* __restrict__ Wt1, const float* __restrict__ b1, ushort_t* __restrict__ Y1,
    int M, int Nc) {
  constexpr int K = 128, BM = 64, LDT = 136;
  __shared__ ushort_t Als[BM * LDT];    // 17.4 KB
  __shared__ ushort_t Bls[128 * LDT];   // 34.8 KB
  int r0 = blockIdx.x * BM;
  int col0 = blockIdx.y * 128;  // column block (gridDim.y = Nc/128)
  int tid = threadIdx.x;
  int rl = tid >> 5;            // 0..7
  int kq = (tid & 31) * 4;
  // stage A once (64 rows, 8 steps)
#pragma unroll
  for (int s = 0; s < 8; ++s) {
    int row = rl + s * 8;
    int grow = r0 + row;
    ushort4 v = make_ushort4(0, 0, 0, 0);
    if (grow < M) {
      if constexpr (sizeof(TA) == 4) {
        float4 f = *reinterpret_cast<const float4*>(Xb + (size_t)grow * K + kq);
        v = make_ushort4(f2b(f.x), f2b(f.y), f2b(f.z), f2b(f.w));
      } else {
        v = *reinterpret_cast<const ushort4*>(Xb + (size_t)grow * K + kq);
      }
    }
    *reinterpret_cast<ushort4*>(&Als[row * LDT + kq]) = v;
  }
  int lane = tid & 63;
  int w = tid >> 6;
  int m0 = (w & 1) * 32;
  int n0 = (w >> 1) * 64;
  int rin = lane & 15, quad = lane >> 4;

  for (int half = 0; half < 2; ++half) {
    const ushort_t* Wt = half ? Wt1 : Wt0;
    const float* bias = half ? b1 : b0;
    ushort_t* Y = half ? Y1 : Y0;
    __syncthreads();  // half0: A-stage visible; half1: prev Bls reads done
#pragma unroll
    for (int s = 0; s < 16; ++s) {
      int row = rl + s * 8;
      ushort4 wv = *reinterpret_cast<const ushort4*>(Wt + (size_t)(col0 + row) * K + kq);
      *reinterpret_cast<ushort4*>(&Bls[row * LDT + kq]) = wv;
    }
    __syncthreads();  // A and B staged
    floatx4 acc[2][4];
#pragma unroll
    for (int i = 0; i < 2; ++i)
#pragma unroll
      for (int j = 0; j < 4; ++j) acc[i][j] = (floatx4){0.f, 0.f, 0.f, 0.f};
#pragma unroll
    for (int kt = 0; kt < 4; ++kt) {
      int ko = kt * 32 + quad * 8;
      bhalf8 af[2], bf[4];
#pragma unroll
      for (int i = 0; i < 2; ++i)
        af[i] = *reinterpret_cast<const bhalf8*>(&Als[(m0 + i * 16 + rin) * LDT + ko]);
#pragma unroll
      for (int i = 0; i < 4; ++i)
        bf[i] = *reinterpret_cast<const bhalf8*>(&Bls[(n0 + i * 16 + rin) * LDT + ko]);
#pragma unroll
      for (int mi = 0; mi < 2; ++mi)
#pragma unroll
        for (int ni = 0; ni < 4; ++ni)
          acc[mi][ni] = __builtin_amdgcn_mfma_f32_16x16x32_bf16(af[mi], bf[ni], acc[mi][ni], 0, 0, 0);
    }
#pragma unroll
    for (int ni = 0; ni < 4; ++ni) {
      int gcol = col0 + n0 + ni * 16 + rin;
      float bb = bias[gcol];
#pragma unroll
      for (int mi = 0; mi < 2; ++mi) {
        int growb = r0 + m0 + mi * 16 + quad * 4;
#pragma unroll
        for (int r = 0; r < 4; ++r) {
          int grow = growb + r;
          if (grow < M) Y[(size_t)grow * Nc + gcol] = f2b(acc[mi][ni][r] + bb);
        }
      }
    }
  }
}

// ---------------- bf16 vector load/store helpers ----------------
template <int VPL>
__device__ __forceinline__ void loadb(const ushort_t* p, float* v) {
  if constexpr (VPL == 2) {
    ushort2 t = *reinterpret_cast<const ushort2*>(p);
    v[0] = b2f(t.x); v[1] = b2f(t.y);
  } else {
    ushort4 t = *reinterpret_cast<const ushort4*>(p);
    v[0] = b2f(t.x); v[1] = b2f(t.y); v[2] = b2f(t.z); v[3] = b2f(t.w);
  }
}
template <int VPL>
__device__ __forceinline__ void storeb(ushort_t* p, const float* v) {
  if constexpr (VPL == 2) {
    *reinterpret_cast<ushort2*>(p) = make_ushort2(f2b(v[0]), f2b(v[1]));
  } else {
    *reinterpret_cast<ushort4*>(p) = make_ushort4(f2b(v[0]), f2b(v[1]), f2b(v[2]), f2b(v[3]));
  }
}

// per-edge logit: leaky-relu(xl+xr+ea@We) . att (ea@We via 8 dot2 f16 MACs/channel)
template <int VPL>
__device__ __forceinline__ float lrelu_dot(const float* xv, const float* rv,
                                           const half2_t (*wepk)[VPL], const float* areg,
                                           const uint_t* ea) {
  float part = 0.f;
#pragma unroll
  for (int j = 0; j < VPL; ++j) {
    float z = xv[j] + rv[j];
#pragma unroll
    for (int k2 = 0; k2 < 8; ++k2) z = dot2acc(ea[k2], wepk[k2][j], z);
    float zl = fmaxf(z, NSLOPE * z);  // leaky-relu (slope<1)
    part = fmaf(zl, areg[j], part);
  }
  return red16(part);  // per-head (16-lane) reduce-broadcast, DPP only
}

// batched softmax update over EB edges
template <int EB, int VPL, int C>
__device__ __forceinline__ void process_group(
    const int* __restrict__ srcp, const uint_t* __restrict__ eah, int j,
    const ushort_t* __restrict__ xl, int lane, const float* rv,
    const half2_t (*wepk)[VPL], const float* areg,
    float& s, float* acc) {
  int sn[EB];
#pragma unroll
  for (int u = 0; u < EB; ++u) sn[u] = srcp[j + u];
  float xv[EB][VPL];
#pragma unroll
  for (int u = 0; u < EB; ++u) loadb<VPL>(xl + (size_t)sn[u] * C + lane * VPL, xv[u]);
  float lg[EB];
#pragma unroll
  for (int u = 0; u < EB; ++u) {
    const uint4* ap4 = reinterpret_cast<const uint4*>(eah + (size_t)(j + u) * 8);
    uint4 e0 = ap4[0], e1 = ap4[1];
    uint_t ea[8] = {e0.x, e0.y, e0.z, e0.w, e1.x, e1.y, e1.z, e1.w};
    lg[u] = lrelu_dot<VPL>(xv[u], rv, wepk, areg, ea);
  }
  float p[EB], ps = 0.f;
#pragma unroll
  for (int u = 0; u < EB; ++u) { p[u] = fexp2(lg[u]); ps += p[u]; }
  s += ps;
#pragma unroll
  for (int jj = 0; jj < VPL; ++jj) {
    float t = p[0] * xv[0][jj];
#pragma unroll
    for (int u = 1; u < EB; ++u) t = fmaf(p[u], xv[u][jj], t);
    acc[jj] += t;
  }
}

// single edge with explicit src + packed ea pairs (self-loop path)
template <int VPL, int C>
__device__ __forceinline__ void process_edge(
    int sn, const uint_t* ea,
    const ushort_t* __restrict__ xl, int lane, const float* rv,
    const half2_t (*wepk)[VPL], const float* areg,
    float& s, float* acc) {
  float xv[VPL];
  loadb<VPL>(xl + (size_t)sn * C + lane * VPL, xv);
  float lg = lrelu_dot<VPL>(xv, rv, wepk, areg, ea);
  float p = fexp2(lg);
  s += p;
#pragma unroll
  for (int jj = 0; jj < VPL; ++jj) acc[jj] = fmaf(p, xv[jj], acc[jj]);
}

// ---------------- fused GATv2 edge+softmax+aggregate: ONE 64-thread block per dst ----
// R4 exact form (best measured: 118.6us). Throughput-capped on beyond-L2 path
// (~3.2 B/cy/CU); all parallelism levers (pipelining, 2-wave, persistent, nt)
// measured null-or-negative. This is the floor for this access pattern.
template <int C, bool FINAL>
__global__ __launch_bounds__(64) void gat_fused_kernel(
    const int* __restrict__ rowptr,
    const int* __restrict__ srcp, const uint_t* __restrict__ eah,
    const uint_t* __restrict__ meanattr_h,
    const ushort_t* __restrict__ xl, const ushort_t* __restrict__ xr,
    const uint_t* __restrict__ wep,   // [8*C] packed f16 k-pairs of We
    const float* __restrict__ atts,   // [C] att * log2(e)
    const float* __restrict__ bias, ushort_t* __restrict__ hout, int N) {
  constexpr int VPL = C / 64;
  const int lane = threadIdx.x & 63;
  int d = blockIdx.x;
  if (d >= N) return;

  half2_t wepk[8][VPL];
  float areg[VPL];
#pragma unroll
  for (int k2 = 0; k2 < 8; ++k2)
#pragma unroll
    for (int jj = 0; jj < VPL; ++jj)
      wepk[k2][jj] = __builtin_bit_cast(half2_t, wep[k2 * C + lane * VPL + jj]);
#pragma unroll
  for (int jj = 0; jj < VPL; ++jj) areg[jj] = atts[lane * VPL + jj];

  int beg = rowptr[d], end = rowptr[d + 1];
  float rv[VPL];
  loadb<VPL>(xr + (size_t)d * C + lane * VPL, rv);

  float s = 0.f;
  float acc[VPL];
#pragma unroll
  for (int jj = 0; jj < VPL; ++jj) acc[jj] = 0.f;

  int j = beg;
  if constexpr (C == 128) {
    for (; j + 8 <= end; j += 8)
      process_group<8, VPL, C>(srcp, eah, j, xl, lane, rv, wepk, areg, s, acc);
  }
  for (; j + 4 <= end; j += 4)
    process_group<4, VPL, C>(srcp, eah, j, xl, lane, rv, wepk, areg, s, acc);
  for (; j + 2 <= end; j += 2)
    process_group<2, VPL, C>(srcp, eah, j, xl, lane, rv, wepk, areg, s, acc);
  for (; j < end; ++j)
    process_group<1, VPL, C>(srcp, eah, j, xl, lane, rv, wepk, areg, s, acc);

  // self loop with mean edge_attr (fill_value='mean')
  {
    const uint4* mp4 = reinterpret_cast<const uint4*>(meanattr_h + (size_t)d * 8);
    uint4 e0 = mp4[0], e1 = mp4[1];
    uint_t ea[8] = {e0.x, e0.y, e0.z, e0.w, e1.x, e1.y, e1.z, e1.w};
    process_edge<VPL, C>(d, ea, xl, lane, rv, wepk, areg, s, acc);
  }

  float inv = 1.f / (s + 1e-16f);
  if constexpr (!FINAL) {
    float res[VPL];
#pragma unroll
    for (int jj = 0; jj < VPL; ++jj) {
      float v = acc[jj] * inv + bias[lane * VPL + jj];
      res[jj] = v > 0.f ? v : 0.f;
    }
    storeb<VPL>(hout + (size_t)d * C + lane * VPL, res);
  } else {
    float v[VPL];
#pragma unroll
    for (int jj = 0; jj < VPL; ++jj) v[jj] = acc[jj] * inv;
#pragma unroll
    for (int jj = 0; jj < VPL; ++jj) {
      v[jj] += __shfl_xor(v[jj], 16);
      v[jj] += __shfl_xor(v[jj], 32);
    }
    if (lane < 16) {
      float res[VPL];
#pragma unroll
      for (int jj = 0; jj < VPL; ++jj) {
        float val = 0.25f * v[jj] + bias[lane * VPL + jj];
        res[jj] = val > 0.f ? val : 0.f;
      }
      storeb<VPL>(hout + (size_t)d * 64 + lane * VPL, res);
    }
  }
}

// ---------------- global mean pool: segmented reduction (batch is SORTED) ----------------
__global__ __launch_bounds__(256) void pool_kernel(
    const ushort_t* __restrict__ h3, const int* __restrict__ batch,
    float* __restrict__ gsum, float* __restrict__ gcnt, int N) {
  const int lane = threadIdx.x & 63;
  const int w = blockIdx.x * (blockDim.x >> 6) + (threadIdx.x >> 6);
  const int nw = gridDim.x * (blockDim.x >> 6);
  const int chunk = (N + nw - 1) / nw;
  int i0 = w * chunk;
  int i1 = i0 + chunk; if (i1 > N) i1 = N;
  if (i0 >= i1) return;
  int cur = batch[i0];
  float acc = 0.f;
  int cnt = 0;
  for (int i = i0; i < i1; ++i) {
    int g = batch[i];
    if (g != cur) {
      atomicAdd(&gsum[(size_t)cur * 64 + lane], acc);
      if (lane == 0) atomicAdd(&gcnt[cur], (float)cnt);
      acc = 0.f; cnt = 0; cur = g;
    }
    acc += b2f(h3[(size_t)i * 64 + lane]);
    ++cnt;
  }
  atomicAdd(&gsum[(size_t)cur * 64 + lane], acc);
  if (lane == 0) atomicAdd(&gcnt[cur], (float)cnt);
}

__global__ void final_kernel(const float* __restrict__ gsum, const float* __restrict__ gcnt,
                             const float* __restrict__ Wlin, const float* __restrict__ blin,
                             float* __restrict__ out) {
  int idx = blockIdx.x * blockDim.x + threadIdx.x;
  if (idx >= GG * 16) return;
  int g = idx >> 4, o = idx & 15;
  float c = gcnt[g];
  c = c > 1.f ? c : 1.f;
  float inv = 1.f / c;
  float acc = blin[o];
  for (int f = 0; f < 64; ++f) acc = fmaf(gsum[(size_t)g * 64 + f] * inv, Wlin[f * 16 + o], acc);
  out[idx] = acc;
}

// ---------------- launch ----------------
extern "C" void kernel_launch(void* const* d_in, const int* in_sizes, int n_in,
                              void* d_out, int out_size, void* d_ws, size_t ws_size,
                              hipStream_t stream) {
  (void)in_sizes; (void)n_in; (void)out_size; (void)ws_size;
  const float* x     = (const float*)d_in[0];
  const int*   eidx  = (const int*)d_in[1];
  const int*   batch = (const int*)d_in[2];
  const float* eattr = (const float*)d_in[3];
  const float* Wl0 = (const float*)d_in[4];  const float* bl0 = (const float*)d_in[5];
  const float* Wr0 = (const float*)d_in[6];  const float* br0 = (const float*)d_in[7];
  const float* We0 = (const float*)d_in[8];  const float* att0 = (const float*)d_in[9];
  const float* bo0 = (const float*)d_in[10];
  const float* Wlh = (const float*)d_in[11]; const float* blh = (const float*)d_in[12];
  const float* Wrh = (const float*)d_in[13]; const float* brh = (const float*)d_in[14];
  const float* Weh = (const float*)d_in[15]; const float* atth = (const float*)d_in[16];
  const float* boh = (const float*)d_in[17];
  const float* Wlf = (const float*)d_in[18]; const float* blf = (const float*)d_in[19];
  const float* Wrf = (const float*)d_in[20]; const float* brf = (const float*)d_in[21];
  const float* Wef = (const float*)d_in[22]; const float* attf = (const float*)d_in[23];
  const float* bof = (const float*)d_in[24];
  const float* Wlin = (const float*)d_in[25]; const float* blin = (const float*)d_in[26];

  const int* src = eidx;
  const int* dst = eidx + EE;

  char* ws = (char*)d_ws;
  size_t off = 0;
  auto take = [&](size_t bytes) -> void* {
    void* p = ws + off;
    off += (bytes + 1023) & ~(size_t)1023;
    return p;
  };
  ushort_t* xl     = (ushort_t*)take((size_t)NN * 256 * 2);
  ushort_t* xr     = (ushort_t*)take((size_t)NN * 256 * 2);
  ushort_t* hb     = (ushort_t*)take((size_t)NN * 128 * 2);   // layer io (bf16)
  uint_t* meanattr_h = (uint_t*)take((size_t)NN * 8 * 4);     // f16 pairs
  // hist, gsum, gcnt adjacent: ONE memset covers all three
  int* hist        = (int*)take((size_t)NN * 4);              // pads to 200704
  float* gsum      = (float*)take((size_t)GG * 64 * 4);       // 16384
  float* gcnt      = (float*)take((size_t)GG * 4);            // 256
  int* rowptr      = (int*)take((size_t)(NN + 1) * 4);
  int* cursor      = (int*)take((size_t)NN * 4);
  int* bsum        = (int*)take(256);
  ushort_t* wtl0   = (ushort_t*)take((size_t)128 * 128 * 2);
  ushort_t* wtr0   = (ushort_t*)take((size_t)128 * 128 * 2);
  ushort_t* wtlh   = (ushort_t*)take((size_t)128 * 128 * 2);
  ushort_t* wtrh   = (ushort_t*)take((size_t)128 * 128 * 2);
  ushort_t* wtlf   = (ushort_t*)take((size_t)256 * 128 * 2);
  ushort_t* wtrf   = (ushort_t*)take((size_t)256 * 128 * 2);
  int* srcp        = (int*)take((size_t)EE * 4);
  uint_t* eah      = (uint_t*)take((size_t)EE * 8 * 4);
  uint_t* we0p     = (uint_t*)take((size_t)8 * 128 * 4);
  uint_t* wehp     = (uint_t*)take((size_t)8 * 128 * 4);
  uint_t* wefp     = (uint_t*)take((size_t)8 * 256 * 4);
  float* att0s     = (float*)take((size_t)128 * 4);
  float* atths     = (float*)take((size_t)128 * 4);
  float* attfs     = (float*)take((size_t)256 * 4);

  // ---- CSR by dst (dst fixed across layers; rebuilt every call) ----
  // hist (padded 200704) + gsum (16384) + gcnt (256) are contiguous in ws
  hipMemsetAsync(hist, 0, 200704 + 16384 + 256, stream);
  hist_kernel<<<(EE / 4 + 255) / 256, 256, 0, stream>>>(dst, hist, EE / 4);
  int nsb = (NN + SCAN_B - 1) / SCAN_B;   // 49 (<= 64 for in-kernel wave reduce)
  scan_block_kernel<<<nsb, SCAN_B, 0, stream>>>(hist, rowptr + 1, bsum, NN);
  add_offsets_kernel<<<nsb, SCAN_B, 0, stream>>>(rowptr, bsum, cursor, NN, nsb);
  scatter_fused_kernel<<<(EE + 255) / 256, 256, 0, stream>>>(dst, src, eattr, cursor, srcp, eah, EE);
  mean_attr_kernel<<<(NN + 3) / 4, 256, 0, stream>>>(rowptr, eah, meanattr_h, NN);
  prep_all_kernel<<<dim3(128, 9), 256, 0, stream>>>(
      Wl0, wtl0, 128, Wr0, wtr0, 128, Wlh, wtlh, 128, Wrh, wtrh, 128,
      Wlf, wtlf, 256, Wrf, wtrf, 256,
      We0, att0, we0p, att0s, Weh, atth, wehp, atths, Wef, attf, wefp, attfs);

  const int GEMM_MB = (NN + 63) / 64;   // 782 blocks (BM=64)

  // ---- Layer 1 (C=128): GEMM reads fp32 x directly (f2b fused into stage) ----
  gemm_bt_dual_bf16<float><<<dim3(GEMM_MB, 1), 256, 0, stream>>>(
      x, wtl0, bl0, xl, wtr0, br0, xr, NN, 128);
  gat_fused_kernel<128, false><<<NN, 64, 0, stream>>>(
      rowptr, srcp, eah, meanattr_h, xl, xr, we0p, att0s, bo0, hb, NN);
  // ---- Layer 2 (C=128) ----
  gemm_bt_dual_bf16<ushort_t><<<dim3(GEMM_MB, 1), 256, 0, stream>>>(
      hb, wtlh, blh, xl, wtrh, brh, xr, NN, 128);
  gat_fused_kernel<128, false><<<NN, 64, 0, stream>>>(
      rowptr, srcp, eah, meanattr_h, xl, xr, wehp, atths, boh, hb, NN);
  // ---- Layer 3 (C=256, mean over heads) ----
  gemm_bt_dual_bf16<ushort_t><<<dim3(GEMM_MB, 2), 256, 0, stream>>>(
      hb, wtlf, blf, xl, wtrf, brf, xr, NN, 256);
  gat_fused_kernel<256, true><<<NN, 64, 0, stream>>>(
      rowptr, srcp, eah, meanattr_h, xl, xr, wefp, attfs, bof, hb, NN);
  // ---- pool + final linear ----
  pool_kernel<<<128, 256, 0, stream>>>(hb, batch, gsum, gcnt, NN);
  final_kernel<<<4, 256, 0, stream>>>(gsum, gcnt, Wlin, blin, (float*)d_out);
}